// Round 2
// baseline (35628.912 us; speedup 1.0000x reference)
//
#include <hip/hip_runtime.h>
#include <math.h>

#define B_   64
#define T_   512
#define IN_  64
#define HID_ 256
#define KTOT 65536   // HID*HID

typedef __attribute__((ext_vector_type(8))) short  short8;
typedef __attribute__((ext_vector_type(4))) float  floatx4;

__device__ __forceinline__ unsigned short f2bf(float f) {
    unsigned int u = __float_as_uint(f);
    u += 0x7FFFu + ((u >> 16) & 1u);          // round-to-nearest-even
    return (unsigned short)(u >> 16);
}
__device__ __forceinline__ float bf2f(unsigned short s) {
    return __uint_as_float(((unsigned int)s) << 16);
}

// ---- once per launch: W_hh fp32 -> bf16 ----------------------------------
__global__ __launch_bounds__(256) void conv_w(const float* __restrict__ W,
                                              unsigned short* __restrict__ Wb)
{
    const size_t idx = ((size_t)blockIdx.x * 256 + threadIdx.x) * 4;
    const float4 v = *(const float4*)(W + idx);
    unsigned int lo = (unsigned int)f2bf(v.x) | ((unsigned int)f2bf(v.y) << 16);
    unsigned int hi = (unsigned int)f2bf(v.z) | ((unsigned int)f2bf(v.w) << 16);
    *(uint2*)(Wb + idx) = make_uint2(lo, hi);
}

// ---- init: rB(bf16), W_inT, zero barrier ---------------------------------
__global__ __launch_bounds__(256) void init_kernel(const float* __restrict__ x0,
                                                   const float* __restrict__ W_in,
                                                   unsigned short* __restrict__ rB,
                                                   float* __restrict__ W_inT,
                                                   unsigned* __restrict__ bar)
{
    const int b = blockIdx.x;   // doubles as k for W_inT (both 64)
    const int i = threadIdx.x;
    rB[b * HID_ + i] = f2bf(tanhf(x0[b * HID_ + i]));
    W_inT[b * HID_ + i] = W_in[i * IN_ + b];
    if (b == 0) {
        for (int j2 = i; j2 < 1024; j2 += 256) bar[j2] = 0u;
    }
}

// fallback-only: x state buffer init
__global__ __launch_bounds__(256) void init_x(const float* __restrict__ x0,
                                              float* __restrict__ x)
{
    const int idx = blockIdx.x * 256 + threadIdx.x;
    x[idx] = x0[idx];
}

// ---- optional precompute: pre[t][b][i] = 0.05*n + 0.2*(b_in + u@W_in^T) --
__global__ __launch_bounds__(256) void pre_kernel(const float* __restrict__ u,
                                                  const float* __restrict__ W_inT,
                                                  const float* __restrict__ b_in,
                                                  const float* __restrict__ noise,
                                                  float* __restrict__ pre)
{
    __shared__ float u_s[4][64];
    const int i  = threadIdx.x;
    const int b  = blockIdx.x >> 2;
    const int t0 = (blockIdx.x & 3) << 7;
    float wcol[64];
    #pragma unroll
    for (int k = 0; k < 64; ++k) wcol[k] = W_inT[(k << 8) + i];
    const float bi = b_in[i];
    for (int tt = 0; tt < 128; tt += 4) {
        __syncthreads();
        u_s[i >> 6][i & 63] = u[b * (T_ * IN_) + (t0 + tt + (i >> 6)) * IN_ + (i & 63)];
        __syncthreads();
        #pragma unroll
        for (int j2 = 0; j2 < 4; ++j2) {
            const int t = t0 + tt + j2;
            float acc = bi;
            #pragma unroll
            for (int k = 0; k < 64; ++k) acc = fmaf(u_s[j2][k], wcol[k], acc);
            pre[t * 16384 + b * HID_ + i] =
                fmaf(0.05f, noise[t * 16384 + b * HID_ + i], 0.2f * acc);
        }
    }
}

// ---- hierarchical grid barrier (16 groups x 32 blocks) -------------------
#define NGRP  16
#define GRPSZ 32

__device__ __forceinline__ void grid_bar(unsigned* bar, int gid, unsigned ep)
{
    __syncthreads();                     // all waves' stores drained (vmcnt 0)
    if (threadIdx.x == 0) {
        __builtin_amdgcn_fence(__ATOMIC_RELEASE, "agent");   // make stores visible
        const unsigned a = __hip_atomic_fetch_add(&bar[gid * 32], 1u,
                               __ATOMIC_ACQ_REL, __HIP_MEMORY_SCOPE_AGENT);
        if (a == ep * GRPSZ - 1u) {      // last block of group
            const unsigned r = __hip_atomic_fetch_add(&bar[512], 1u,
                                   __ATOMIC_ACQ_REL, __HIP_MEMORY_SCOPE_AGENT);
            if (r == ep * NGRP - 1u) {   // last group
                __hip_atomic_store(&bar[544], ep, __ATOMIC_RELEASE,
                                   __HIP_MEMORY_SCOPE_AGENT);
            }
        }
        while (__hip_atomic_load(&bar[544], __ATOMIC_RELAXED,
                                 __HIP_MEMORY_SCOPE_AGENT) < ep) {
            __builtin_amdgcn_s_sleep(1);
        }
        __builtin_amdgcn_fence(__ATOMIC_ACQUIRE, "agent");   // invalidate caches
    }
    __syncthreads();
}

// ---- persistent cooperative kernel: all 512 steps ------------------------
// 512 blocks x 256 thr, 2 blocks/CU. Block (ig,c): i-group ig (64 i),
// k-slice c (j in {2c,2c+1}, k2 in [0,256)).
// W resident: i-subtiles [iq*32,iq*32+16) in VGPR (wv[16], 64 regs),
//             i-subtiles [iq*32+16,iq*32+32) in LDS W2 (32KB).
// Per wave w: bq=w>>1 (b rows 32bq..+32), iq=w&1 (i cols i0+32iq..+32).
// D[b,i] = rj0*sum_k2 r_k2*W[i,2c,k2] + rj1*sum_k2 r_k2*W[i,2c+1,k2]
// Phase C: block owns 32 pairs [blk*32, blk*32+32); tid&31 = pair lane,
// tid>>5 = slice-group (16 slices each); fully coalesced 128B reads.
__global__ __launch_bounds__(256, 2) void persist_kernel(
    const unsigned short* __restrict__ Wb,
    unsigned short* __restrict__ rB,
    float* __restrict__ P,
    const float* __restrict__ pre,
    const float* __restrict__ u,
    const float* __restrict__ W_inT,
    const float* __restrict__ b_in,
    const float* __restrict__ noise,
    const float* __restrict__ x0,
    float* __restrict__ traj,
    float* __restrict__ xf,
    unsigned* bar,
    int use_pre)
{
    __shared__ unsigned short W2[2][16][512];   // odd i-subtiles of this i-group
    __shared__ float red[128];                  // phase-C cross-wave reduce

    const int tid = threadIdx.x;
    const int l   = tid & 63;
    const int w   = tid >> 6;
    const int m   = l & 15;
    const int q   = l >> 4;
    const int blk = blockIdx.x;
    const int ig  = blk >> 7;
    const int c   = blk & 127;
    const int i0  = ig << 6;
    const int bq  = w >> 1;
    const int iq  = w & 1;

    // stage LDS W2: wave w stages subtile st=w&1, kc range (w>>1)*8..+8
    {
        const int st = w & 1;
        const int kh = (w >> 1) << 3;
        const unsigned short* src = Wb + (size_t)(i0 + (st << 5) + 16 + m) * KTOT
                                       + (c << 9) + (q << 3);
        #pragma unroll
        for (int kk = 0; kk < 8; ++kk) {
            const int kc = kh + kk;
            *(uint4*)(&W2[st][kc][l << 3]) = *(const uint4*)(src + (kc << 5));
        }
    }
    // VGPR W: even subtile of this wave's i-range (B-fragment layout direct)
    short8 wv[16];
    {
        const unsigned short* src = Wb + (size_t)(i0 + (iq << 5) + m) * KTOT
                                       + (c << 9) + (q << 3);
        #pragma unroll
        for (int kc = 0; kc < 16; ++kc) wv[kc] = *(const short8*)(src + (kc << 5));
    }

    // phase-G A-fragment pointers (rows bq*32+m and bq*32+16+m)
    const unsigned short* rA0 = rB + ((bq << 5) + m) * HID_ + (q << 3);
    const unsigned short* rA1 = rA0 + 16 * HID_;

    // phase-C mapping: block owns pairs [blk*32, blk*32+32)
    const int own   = tid & 31;           // owned-pair lane
    const int pair0 = blk << 5;
    const int sgrp  = tid >> 5;           // 0..7 slice group
    const int cb    = (pair0 + own) >> 8;
    const int ci    = (pair0 + own) & 255;
    float x_reg = x0[pair0 + own];        // dup x8, in-bounds (max 16383)

    const int gid = blk >> 5;
    const floatx4 z4 = {0.f, 0.f, 0.f, 0.f};

    __syncthreads();   // LDS staged

    for (int t = 0; t < T_; ++t) {
        // ================= phase G =================
        floatx4 aA[2][2], aB[2][2];
        aA[0][0] = z4; aA[0][1] = z4; aA[1][0] = z4; aA[1][1] = z4;
        aB[0][0] = z4; aB[0][1] = z4; aB[1][0] = z4; aB[1][1] = z4;

        #pragma unroll
        for (int kc = 0; kc < 8; ++kc) {
            const short8 af0 = *(const short8*)(rA0 + (kc << 5));
            const short8 af1 = *(const short8*)(rA1 + (kc << 5));
            const short8 wEA = wv[kc];
            const short8 wEB = wv[kc + 8];
            const short8 wOA = *(const short8*)(&W2[iq][kc][l << 3]);
            const short8 wOB = *(const short8*)(&W2[iq][kc + 8][l << 3]);
            aA[0][0] = __builtin_amdgcn_mfma_f32_16x16x32_bf16(af0, wEA, aA[0][0], 0, 0, 0);
            aA[0][1] = __builtin_amdgcn_mfma_f32_16x16x32_bf16(af0, wOA, aA[0][1], 0, 0, 0);
            aA[1][0] = __builtin_amdgcn_mfma_f32_16x16x32_bf16(af1, wEA, aA[1][0], 0, 0, 0);
            aA[1][1] = __builtin_amdgcn_mfma_f32_16x16x32_bf16(af1, wOA, aA[1][1], 0, 0, 0);
            aB[0][0] = __builtin_amdgcn_mfma_f32_16x16x32_bf16(af0, wEB, aB[0][0], 0, 0, 0);
            aB[0][1] = __builtin_amdgcn_mfma_f32_16x16x32_bf16(af0, wOB, aB[0][1], 0, 0, 0);
            aB[1][0] = __builtin_amdgcn_mfma_f32_16x16x32_bf16(af1, wEB, aB[1][0], 0, 0, 0);
            aB[1][1] = __builtin_amdgcn_mfma_f32_16x16x32_bf16(af1, wOB, aB[1][1], 0, 0, 0);
        }

        // epilogue: D = rj0*accA + rj1*accB (fp32 output-side scaling)
        const unsigned rjp = *(const unsigned*)(rB + ((bq << 5) + (l & 31)) * HID_ + (c << 1));
        #pragma unroll
        for (int bt = 0; bt < 2; ++bt) {
            #pragma unroll
            for (int reg = 0; reg < 4; ++reg) {
                const int rl = (bt << 4) + (q << 2) + reg;
                const unsigned rjv = (unsigned)__shfl((int)rjp, rl, 64);
                const float rj0 = bf2f((unsigned short)(rjv & 0xffffu));
                const float rj1 = bf2f((unsigned short)(rjv >> 16));
                float* dst = P + (c << 14) + (((bq << 5) + rl) << 8) + i0 + (iq << 5) + m;
                dst[0]  = rj0 * aA[bt][0][reg] + rj1 * aB[bt][0][reg];
                dst[16] = rj0 * aA[bt][1][reg] + rj1 * aB[bt][1][reg];
            }
        }

        grid_bar(bar, gid, (unsigned)(2 * t + 1));

        // ================= phase C =================
        {
            // thread reads slices [sgrp*16, sgrp*16+16) at pair pair0+own
            const float* Pp = P + (size_t)(sgrp << 4) * 16384 + pair0 + own;
            float s0 = 0.f, s1 = 0.f, s2 = 0.f, s3 = 0.f;
            #pragma unroll
            for (int ss = 0; ss < 16; ss += 4) {
                s0 += Pp[(size_t)(ss + 0) * 16384];
                s1 += Pp[(size_t)(ss + 1) * 16384];
                s2 += Pp[(size_t)(ss + 2) * 16384];
                s3 += Pp[(size_t)(ss + 3) * 16384];
            }
            float part = (s0 + s1) + (s2 + s3);
            part += __shfl_xor(part, 32, 64);            // pair sgrp g with g^1
            if ((tid & 32) == 0) red[(w << 5) + own] = part;
            __syncthreads();
            const float hidden = red[own] + red[32 + own] + red[64 + own] + red[96 + own];

            float pn;
            if (use_pre) {
                pn = pre[(t << 14) + pair0 + own];
            } else {
                float inp = b_in[ci];
                const float* ur = u + cb * (T_ * IN_) + (t << 6);
                #pragma unroll
                for (int k = 0; k < 64; ++k)
                    inp = fmaf(ur[k], W_inT[(k << 8) + ci], inp);
                pn = fmaf(0.05f, noise[((size_t)t << 14) + pair0 + own], 0.2f * inp);
            }
            const float xn = fmaf(0.8f, x_reg, fmaf(0.2f, hidden, pn));
            x_reg = xn;
            if (tid < 32) {
                traj[(size_t)cb * (T_ * HID_) + (t << 8) + ci] = xn;
                rB[pair0 + own] = f2bf(tanhf(xn));
                if (t == T_ - 1) xf[pair0 + own] = xn;
            }
        }

        grid_bar(bar, gid, (unsigned)(2 * t + 2));
    }
}

// ======================= fallback path (known-good) =======================
__global__ __launch_bounds__(256) void gemm_step(const unsigned short* __restrict__ Wb,
                                                 const unsigned short* __restrict__ rB,
                                                 float* __restrict__ P)
{
    __shared__ unsigned short A_lds[32768];

    const int tid = threadIdx.x;
    const int l   = tid & 63;
    const int w   = tid >> 6;
    const int m   = l & 15;
    const int q   = l >> 4;
    const int ig  = blockIdx.x >> 7;
    const int c   = blockIdx.x & 127;
    const int i0  = ig << 6;

    {
        const unsigned short* src = Wb + (size_t)(i0 + (w << 4) + m) * KTOT
                                       + (c << 9) + (q << 3);
        unsigned short* dst = &A_lds[(w << 13) + (l << 3)];
        #pragma unroll
        for (int kc = 0; kc < 16; ++kc) {
            uint4 v = *(const uint4*)(src + (kc << 5));
            *(uint4*)(dst + (kc << 9)) = v;
        }
    }

    const int b = (w << 4) + m;
    const float rj0 = bf2f(rB[b * HID_ + 2 * c]);
    const float rj1 = bf2f(rB[b * HID_ + 2 * c + 1]);
    const unsigned short* rrow = rB + b * HID_ + (q << 3);

    floatx4 acc0 = {0.f, 0.f, 0.f, 0.f};
    floatx4 acc1 = {0.f, 0.f, 0.f, 0.f};
    floatx4 acc2 = {0.f, 0.f, 0.f, 0.f};
    floatx4 acc3 = {0.f, 0.f, 0.f, 0.f};

    __syncthreads();

    #pragma unroll
    for (int kc = 0; kc < 16; ++kc) {
        const float rj = (kc < 8) ? rj0 : rj1;
        const uint4 rv = *(const uint4*)(rrow + ((kc & 7) << 5));
        short8 gfrag;
        {
            unsigned int* gp = (unsigned int*)&gfrag;
            const unsigned short* rs = (const unsigned short*)&rv;
            #pragma unroll
            for (int p = 0; p < 4; ++p) {
                const float lo = bf2f(rs[2 * p])     * rj;
                const float hi = bf2f(rs[2 * p + 1]) * rj;
                gp[p] = (unsigned int)f2bf(lo) | ((unsigned int)f2bf(hi) << 16);
            }
        }
        const unsigned short* ab = &A_lds[(kc << 9) + (l << 3)];
        const short8 w0 = *(const short8*)(ab);
        const short8 w1 = *(const short8*)(ab + 8192);
        const short8 w2 = *(const short8*)(ab + 16384);
        const short8 w3 = *(const short8*)(ab + 24576);
        acc0 = __builtin_amdgcn_mfma_f32_16x16x32_bf16(gfrag, w0, acc0, 0, 0, 0);
        acc1 = __builtin_amdgcn_mfma_f32_16x16x32_bf16(gfrag, w1, acc1, 0, 0, 0);
        acc2 = __builtin_amdgcn_mfma_f32_16x16x32_bf16(gfrag, w2, acc2, 0, 0, 0);
        acc3 = __builtin_amdgcn_mfma_f32_16x16x32_bf16(gfrag, w3, acc3, 0, 0, 0);
    }

    #pragma unroll
    for (int reg = 0; reg < 4; ++reg) {
        float* dst = P + (c << 14) + ((w << 4) + (q << 2) + reg) * HID_ + i0 + m;
        dst[0]  = acc0[reg];
        dst[16] = acc1[reg];
        dst[32] = acc2[reg];
        dst[48] = acc3[reg];
    }
}

__global__ __launch_bounds__(64) void combine_step(const float* __restrict__ P,
                                                   const float* __restrict__ noise,
                                                   const float* __restrict__ u,
                                                   const float* __restrict__ W_inT,
                                                   const float* __restrict__ b_in,
                                                   float* __restrict__ x,
                                                   unsigned short* __restrict__ rB,
                                                   float* __restrict__ traj,
                                                   int t)
{
    const int b = blockIdx.x >> 2;
    const int i = ((blockIdx.x & 3) << 6) + threadIdx.x;

    __shared__ float u_s[64];
    u_s[threadIdx.x] = u[b * (T_ * IN_) + t * IN_ + threadIdx.x];
    __syncthreads();

    const float* Pp = P + b * HID_ + i;
    float s0 = 0.f, s1 = 0.f, s2 = 0.f, s3 = 0.f;
    #pragma unroll 4
    for (int cc = 0; cc < 128; cc += 4) {
        s0 += Pp[(cc + 0) * 16384];
        s1 += Pp[(cc + 1) * 16384];
        s2 += Pp[(cc + 2) * 16384];
        s3 += Pp[(cc + 3) * 16384];
    }
    const float hidden = (s0 + s1) + (s2 + s3);

    float inp = b_in[i];
    #pragma unroll
    for (int k = 0; k < 64; ++k) inp += u_s[k] * W_inT[k * HID_ + i];

    const float xo = x[b * HID_ + i];
    const float n  = noise[t * (B_ * HID_) + b * HID_ + i];
    const float xn = 0.8f * xo + 0.05f * n + 0.2f * (hidden + inp);

    x[b * HID_ + i] = xn;
    traj[(size_t)b * (T_ * HID_) + t * HID_ + i] = xn;
    rB[b * HID_ + i] = f2bf(tanhf(xn));
}

__global__ __launch_bounds__(256) void copy_xfinal(const float* __restrict__ x,
                                                   float* __restrict__ xf)
{
    const int idx = blockIdx.x * 256 + threadIdx.x;
    xf[idx] = x[idx];
}

// ---- output projection (fp32) --------------------------------------------
__global__ __launch_bounds__(256) void output_kernel(const float* __restrict__ traj,
                                                     const float* __restrict__ W_out,
                                                     const float* __restrict__ b_out,
                                                     float* __restrict__ out)
{
    __shared__ float r_s[16 * 256];
    __shared__ float Wt[64 * 65];

    const int tid = threadIdx.x;
    const int b   = blockIdx.x >> 5;
    const int t0  = (blockIdx.x & 31) << 4;

    #pragma unroll
    for (int r = 0; r < 16; ++r) {
        r_s[r * 256 + tid] = tanhf(traj[(size_t)b * (T_ * HID_) + (t0 + r) * HID_ + tid]);
    }

    const int o  = tid & 63;
    const int rg = tid >> 6;
    float acc0 = b_out[o];
    float acc1 = acc0, acc2 = acc0, acc3 = acc0;

    for (int ib = 0; ib < 4; ++ib) {
        __syncthreads();
        #pragma unroll
        for (int r = 0; r < 16; ++r) {
            const int f  = (r << 8) + tid;
            const int oo = f >> 6;
            const int il = f & 63;
            Wt[il * 65 + oo] = W_out[oo * 256 + (ib << 6) + il];
        }
        __syncthreads();
        #pragma unroll 16
        for (int il = 0; il < 64; ++il) {
            const float ww = Wt[il * 65 + o];
            const int i = (ib << 6) + il;
            acc0 += r_s[(rg * 4 + 0) * 256 + i] * ww;
            acc1 += r_s[(rg * 4 + 1) * 256 + i] * ww;
            acc2 += r_s[(rg * 4 + 2) * 256 + i] * ww;
            acc3 += r_s[(rg * 4 + 3) * 256 + i] * ww;
        }
    }
    float* ob = out + b * (T_ * IN_) + (t0 + (rg << 2)) * IN_ + o;
    ob[0 * IN_] = acc0;
    ob[1 * IN_] = acc1;
    ob[2 * IN_] = acc2;
    ob[3 * IN_] = acc3;
}

extern "C" void kernel_launch(void* const* d_in, const int* in_sizes, int n_in,
                              void* d_out, int out_size, void* d_ws, size_t ws_size,
                              hipStream_t stream)
{
    const float* u     = (const float*)d_in[0];
    const float* x0    = (const float*)d_in[1];
    const float* noise = (const float*)d_in[2];
    const float* W_hh  = (const float*)d_in[3];
    const float* W_in  = (const float*)d_in[4];
    const float* b_in  = (const float*)d_in[5];
    const float* W_out = (const float*)d_in[6];
    const float* b_out = (const float*)d_in[7];

    float* out  = (float*)d_out;
    float* xf   = out + 2097152;            // [B][HID]
    float* traj = out + 2097152 + 16384;    // [B][T][HID]

    // ws byte layout:
    //   P     : 0          (8,388,608)
    //   Wb    : 8,388,608  (33,554,432)
    //   rB    : 41,943,040 (32,768)
    //   W_inT : 41,975,808 (65,536)
    //   bar   : 42,041,344 (4,096)         [coop path]
    //   x     : 42,041,344 (65,536)        [fallback only, overlaps bar]
    //   pre   : 42,110,976 (33,554,432)    [coop path, if ws allows]
    char* wsb = (char*)d_ws;
    float*          P     = (float*)(wsb);
    unsigned short* Wb    = (unsigned short*)(wsb + 8388608ull);
    unsigned short* rB    = (unsigned short*)(wsb + 41943040ull);
    float*          W_inT = (float*)(wsb + 41975808ull);
    unsigned*       bar   = (unsigned*)(wsb + 42041344ull);
    float*          x     = (float*)(wsb + 42041344ull);
    float*          pre   = (float*)(wsb + 42110976ull);
    const int use_pre = (ws_size >= 42110976ull + 33554432ull) ? 1 : 0;

    conv_w<<<16384, 256, 0, stream>>>(W_hh, Wb);
    init_kernel<<<64, 256, 0, stream>>>(x0, W_in, rB, W_inT, bar);
    if (use_pre) pre_kernel<<<256, 256, 0, stream>>>(u, W_inT, b_in, noise, pre);

    // ---- persistent cooperative path ----
    {
        const unsigned short* a_Wb   = Wb;
        unsigned short*       a_rB   = rB;
        float*                a_P    = P;
        const float*          a_pre  = pre;
        const float*          a_u    = u;
        const float*          a_WinT = W_inT;
        const float*          a_bin  = b_in;
        const float*          a_nz   = noise;
        const float*          a_x0   = x0;
        float*                a_traj = traj;
        float*                a_xf   = xf;
        unsigned*             a_bar  = bar;
        int                   a_up   = use_pre;
        void* args[] = { &a_Wb, &a_rB, &a_P, &a_pre, &a_u, &a_WinT, &a_bin,
                         &a_nz, &a_x0, &a_traj, &a_xf, &a_bar, &a_up };
        hipError_t e = hipLaunchCooperativeKernel(persist_kernel, dim3(512), dim3(256),
                                                  args, 0, stream);
        if (e == hipSuccess) {
            output_kernel<<<2048, 256, 0, stream>>>(traj, W_out, b_out, out);
            return;
        }
    }

    // ---- fallback: per-step launches (previous known-good path) ----
    init_x<<<64, 256, 0, stream>>>(x0, x);
    for (int t = 0; t < T_; ++t) {
        gemm_step<<<512, 256, 0, stream>>>(Wb, rB, P);
        combine_step<<<256, 64, 0, stream>>>(P, noise, u, W_inT, b_in, x, rB, traj, t);
    }
    copy_xfinal<<<64, 256, 0, stream>>>(x, xf);
    output_kernel<<<2048, 256, 0, stream>>>(traj, W_out, b_out, out);
}

// Round 4
// 6118.575 us; speedup vs baseline: 5.8231x; 5.8231x over previous
//
#include <hip/hip_runtime.h>
#include <math.h>

#define B_   64
#define T_   512
#define IN_  64
#define HID_ 256
#define KTOT 65536   // HID*HID

typedef __attribute__((ext_vector_type(8))) short  short8;
typedef __attribute__((ext_vector_type(4))) float  floatx4;

__device__ __forceinline__ unsigned short f2bf(float f) {
    unsigned int u = __float_as_uint(f);
    u += 0x7FFFu + ((u >> 16) & 1u);          // round-to-nearest-even
    return (unsigned short)(u >> 16);
}
__device__ __forceinline__ float bf2f(unsigned short s) {
    return __uint_as_float(((unsigned int)s) << 16);
}

// coherent (agent-scope, cache-bypassing -> memory-side LLC) accesses
__device__ __forceinline__ void cstore(float* p, float v) {
    __hip_atomic_store(p, v, __ATOMIC_RELAXED, __HIP_MEMORY_SCOPE_AGENT);
}
__device__ __forceinline__ float cload(const float* p) {
    return __hip_atomic_load((float*)p, __ATOMIC_RELAXED, __HIP_MEMORY_SCOPE_AGENT);
}
__device__ __forceinline__ void cstore_u32(unsigned* p, unsigned v) {
    __hip_atomic_store(p, v, __ATOMIC_RELAXED, __HIP_MEMORY_SCOPE_AGENT);
}
__device__ __forceinline__ unsigned long long cload_u64(const unsigned long long* p) {
    return __hip_atomic_load((unsigned long long*)p, __ATOMIC_RELAXED,
                             __HIP_MEMORY_SCOPE_AGENT);
}

// ---- fallback only: W_hh fp32 -> bf16 ------------------------------------
__global__ __launch_bounds__(256) void conv_w(const float* __restrict__ W,
                                              unsigned short* __restrict__ Wb)
{
    const size_t idx = ((size_t)blockIdx.x * 256 + threadIdx.x) * 4;
    const float4 v = *(const float4*)(W + idx);
    unsigned int lo = (unsigned int)f2bf(v.x) | ((unsigned int)f2bf(v.y) << 16);
    unsigned int hi = (unsigned int)f2bf(v.z) | ((unsigned int)f2bf(v.w) << 16);
    *(uint2*)(Wb + idx) = make_uint2(lo, hi);
}

// ---- init: rB(bf16), W_inT, zero barrier ---------------------------------
__global__ __launch_bounds__(256) void init_kernel(const float* __restrict__ x0,
                                                   const float* __restrict__ W_in,
                                                   unsigned short* __restrict__ rB,
                                                   float* __restrict__ W_inT,
                                                   unsigned* __restrict__ bar)
{
    const int b = blockIdx.x;   // doubles as k for W_inT (both 64)
    const int i = threadIdx.x;
    rB[b * HID_ + i] = f2bf(tanhf(x0[b * HID_ + i]));
    W_inT[b * HID_ + i] = W_in[i * IN_ + b];
    if (b == 0) {
        for (int j2 = i; j2 < 1024; j2 += 256) bar[j2] = 0u;
    }
}

// fallback-only: x state buffer init
__global__ __launch_bounds__(256) void init_x(const float* __restrict__ x0,
                                              float* __restrict__ x)
{
    const int idx = blockIdx.x * 256 + threadIdx.x;
    x[idx] = x0[idx];
}

// ---- optional precompute: pre[t][b][i] = 0.05*n + 0.2*(b_in + u@W_in^T) --
__global__ __launch_bounds__(256) void pre_kernel(const float* __restrict__ u,
                                                  const float* __restrict__ W_inT,
                                                  const float* __restrict__ b_in,
                                                  const float* __restrict__ noise,
                                                  float* __restrict__ pre)
{
    __shared__ float u_s[4][64];
    const int i  = threadIdx.x;
    const int b  = blockIdx.x >> 2;
    const int t0 = (blockIdx.x & 3) << 7;
    float wcol[64];
    #pragma unroll
    for (int k = 0; k < 64; ++k) wcol[k] = W_inT[(k << 8) + i];
    const float bi = b_in[i];
    for (int tt = 0; tt < 128; tt += 4) {
        __syncthreads();
        u_s[i >> 6][i & 63] = u[b * (T_ * IN_) + (t0 + tt + (i >> 6)) * IN_ + (i & 63)];
        __syncthreads();
        #pragma unroll
        for (int j2 = 0; j2 < 4; ++j2) {
            const int t = t0 + tt + j2;
            float acc = bi;
            #pragma unroll
            for (int k = 0; k < 64; ++k) acc = fmaf(u_s[j2][k], wcol[k], acc);
            pre[t * 16384 + b * HID_ + i] =
                fmaf(0.05f, noise[t * 16384 + b * HID_ + i], 0.2f * acc);
        }
    }
}

// ---- control-only hierarchical grid barrier (16 groups x 32 blocks) ------
// Relaxed agent-scope atomics only (no cache-walk fences). Data exchanged
// between blocks uses coherent (sc0 sc1) accesses, so no wb/inv is needed.
// Timeout + poison flag: a stall aborts the kernel instead of hanging GPU.
#define NGRP  16
#define GRPSZ 32

__device__ __forceinline__ int grid_bar(unsigned* bar, int gid, unsigned ep,
                                        int* abort_s)
{
    __syncthreads();                     // drains vmcnt: coherent stores retired
    if (threadIdx.x == 0) {
        int poison = 0;
        const unsigned a = __hip_atomic_fetch_add(&bar[gid * 32], 1u,
                               __ATOMIC_RELAXED, __HIP_MEMORY_SCOPE_AGENT);
        if (a == ep * GRPSZ - 1u) {      // last block of group
            const unsigned r = __hip_atomic_fetch_add(&bar[512], 1u,
                                   __ATOMIC_RELAXED, __HIP_MEMORY_SCOPE_AGENT);
            if (r == ep * NGRP - 1u) {   // last group: release
                __hip_atomic_store(&bar[544], ep, __ATOMIC_RELAXED,
                                   __HIP_MEMORY_SCOPE_AGENT);
            }
        }
        unsigned spins = 0;
        for (;;) {
            const unsigned f = __hip_atomic_load(&bar[544], __ATOMIC_RELAXED,
                                                 __HIP_MEMORY_SCOPE_AGENT);
            if (f >= ep) break;
            if ((spins & 63u) == 0u) {
                if (__hip_atomic_load(&bar[560], __ATOMIC_RELAXED,
                                      __HIP_MEMORY_SCOPE_AGENT) != 0u) {
                    poison = 1; break;
                }
            }
            if (++spins > 1000000u) {    // ~0.3 s: declare deadlock, poison all
                __hip_atomic_store(&bar[560], 1u, __ATOMIC_RELAXED,
                                   __HIP_MEMORY_SCOPE_AGENT);
                poison = 1; break;
            }
            __builtin_amdgcn_s_sleep(1);
        }
        *abort_s = poison;
    }
    __syncthreads();
    return *abort_s;
}

// ---- persistent cooperative kernel: all 512 steps ------------------------
// 512 blocks x 256 thr, 2 blocks/CU. Block (ig,kg): i-range [ig*16,+16),
// j-range [kg*8,+8).  Full W slice (16 i x 8 j x 256 k2 bf16 = 64KB) lives
// in VGPRs: wave w holds j-pair (kg*8+2w, +1) -> 16 x short8 = 64 VGPR/lane.
// Per step: stage r[64][256] (ring slot t, coherent u64 loads from LLC)
// into swizzled LDS; 4 waves compute D[64][16] over their 2 j's (scaled by
// r_j fp32); cross-wave LDS reduce; write P[kg] (2MB total) coherent.
// Phase C: sum 32 kg-slices (coherent loads), state update, write r into
// ring slot t+1 (coherent packed u32).
__global__ __launch_bounds__(256, 2) void persist_kernel(
    const float* __restrict__ W_hh,
    unsigned short* __restrict__ ring,   // 513 slots x 16384 ushorts
    float* __restrict__ P,               // [32][64][256] f32
    const float* __restrict__ pre,
    const float* __restrict__ u,
    const float* __restrict__ W_inT,
    const float* __restrict__ b_in,
    const float* __restrict__ noise,
    const float* __restrict__ x0,
    float* __restrict__ traj,
    float* __restrict__ xf,
    unsigned* bar,
    int use_pre)
{
    __shared__ unsigned short rL[16384];     // 32 KB swizzled r[64][256]
    __shared__ float Wr[3][4][64][4];        // 12 KB wave partials
    __shared__ float red[128];
    __shared__ int abort_s;

    const int tid = threadIdx.x;
    const int l   = tid & 63;
    const int w   = tid >> 6;        // wave 0..3
    const int m   = l & 15;
    const int q   = l >> 4;
    const int blk = blockIdx.x;
    const int ig  = blk >> 5;        // i-group 0..15
    const int kg  = blk & 31;        // j-group 0..31
    const int i0  = ig << 4;
    const int j0  = (kg << 3) + (w << 1);   // this wave's even j

    // ---- W residency: convert fp32 -> bf16 into 16 x short8 (64 VGPR) ----
    short8 wv[16];
    {
        const float* s0 = W_hh + (size_t)(i0 + m) * KTOT + (j0 << 8) + (q << 3);
        #pragma unroll
        for (int kc = 0; kc < 8; ++kc) {
            #pragma unroll
            for (int half = 0; half < 2; ++half) {
                const float* sp = s0 + (half << 8) + (kc << 5);
                const float4 a = *(const float4*)(sp);
                const float4 bv = *(const float4*)(sp + 4);
                unsigned* gp = (unsigned*)&wv[kc + (half << 3)];
                gp[0] = (unsigned)f2bf(a.x)  | ((unsigned)f2bf(a.y)  << 16);
                gp[1] = (unsigned)f2bf(a.z)  | ((unsigned)f2bf(a.w)  << 16);
                gp[2] = (unsigned)f2bf(bv.x) | ((unsigned)f2bf(bv.y) << 16);
                gp[3] = (unsigned)f2bf(bv.z) | ((unsigned)f2bf(bv.w) << 16);
            }
        }
    }

    // phase-C mapping: block owns pairs [blk*32, blk*32+32)
    const int own   = tid & 31;
    const int pair0 = blk << 5;
    const int sgrp  = tid >> 5;           // 0..7, reads kg-slices [4*sgrp,+4)
    const int cb    = (pair0 + own) >> 8; // uniform per block
    const int ci    = (pair0 + own) & 255;
    float x_reg = x0[pair0 + own];

    const int gid = blk >> 5;
    const floatx4 z4 = {0.f, 0.f, 0.f, 0.f};

    for (int t = 0; t < T_; ++t) {
        // ---- stage r (ring slot t) -> rL, XOR-swizzled; coherent u64 loads
        {
            unsigned long long* src = (unsigned long long*)(ring + (size_t)t * 16384);
            #pragma unroll
            for (int j2 = 0; j2 < 16; ++j2) {
                const int u2 = (j2 << 8) + tid;        // 0..4095
                const unsigned long long v = cload_u64(&src[u2]);
                const int row = u2 >> 6;               // 0..63
                const int c4  = (u2 & 63) << 2;        // ushort col, 4-aligned
                *(unsigned long long*)&rL[(row << 8) + (c4 ^ ((row & 7) << 3))] = v;
            }
        }
        __syncthreads();

        // ---- phase G: D[64][16] partial over j0, j0+1 ----
        floatx4 aA[4], aB[4];
        #pragma unroll
        for (int mt = 0; mt < 4; ++mt) { aA[mt] = z4; aB[mt] = z4; }

        #pragma unroll
        for (int kc = 0; kc < 8; ++kc) {
            const int cc = (q << 3) + (kc << 5);
            #pragma unroll
            for (int mt = 0; mt < 4; ++mt) {
                const int row = (mt << 4) + m;
                const short8 af = *(const short8*)&rL[(row << 8) + (cc ^ ((row & 7) << 3))];
                aA[mt] = __builtin_amdgcn_mfma_f32_16x16x32_bf16(af, wv[kc],     aA[mt], 0, 0, 0);
                aB[mt] = __builtin_amdgcn_mfma_f32_16x16x32_bf16(af, wv[kc + 8], aB[mt], 0, 0, 0);
            }
        }

        // scale by r_j (fp32 output-side) -> per-wave partial
        floatx4 pd[4];
        #pragma unroll
        for (int mt = 0; mt < 4; ++mt) {
            #pragma unroll
            for (int reg = 0; reg < 4; ++reg) {
                const int b = (mt << 4) + (q << 2) + reg;
                const unsigned rr = *(const unsigned*)&rL[(b << 8) + (j0 ^ ((b & 7) << 3))];
                pd[mt][reg] = bf2f((unsigned short)(rr & 0xffffu)) * aA[mt][reg]
                            + bf2f((unsigned short)(rr >> 16))     * aB[mt][reg];
            }
        }

        // cross-wave reduce (waves 1..3 -> LDS, wave 0 sums + stores)
        if (w > 0) {
            #pragma unroll
            for (int mt = 0; mt < 4; ++mt) *(floatx4*)&Wr[w - 1][mt][l][0] = pd[mt];
        }
        __syncthreads();
        if (w == 0) {
            #pragma unroll
            for (int mt = 0; mt < 4; ++mt) {
                floatx4 s = pd[mt];
                s += *(const floatx4*)&Wr[0][mt][l][0];
                s += *(const floatx4*)&Wr[1][mt][l][0];
                s += *(const floatx4*)&Wr[2][mt][l][0];
                #pragma unroll
                for (int reg = 0; reg < 4; ++reg) {
                    const int b = (mt << 4) + (q << 2) + reg;
                    cstore(&P[(kg << 14) + (b << 8) + i0 + m], s[reg]);
                }
            }
        }

        if (grid_bar(bar, gid, (unsigned)(2 * t + 1), &abort_s)) break;

        // ---- phase C ----
        {
            const float* Pp = P + (size_t)(sgrp << 2) * 16384 + pair0 + own;
            float part = cload(Pp) + cload(Pp + 16384)
                       + cload(Pp + 2 * 16384) + cload(Pp + 3 * 16384);
            part += __shfl_xor(part, 32, 64);
            if ((tid & 32) == 0) red[(w << 5) + own] = part;
            __syncthreads();
            const float hidden = red[own] + red[32 + own] + red[64 + own] + red[96 + own];

            float pn;
            if (use_pre) {
                pn = pre[(t << 14) + pair0 + own];
            } else {
                float inp = b_in[ci];
                const float* ur = u + cb * (T_ * IN_) + (t << 6);
                #pragma unroll
                for (int k = 0; k < 64; ++k)
                    inp = fmaf(ur[k], W_inT[(k << 8) + ci], inp);
                pn = fmaf(0.05f, noise[((size_t)t << 14) + pair0 + own], 0.2f * inp);
            }
            const float xn = fmaf(0.8f, x_reg, fmaf(0.2f, hidden, pn));
            x_reg = xn;

            const unsigned short rb = f2bf(tanhf(xn));
            const unsigned nb = (unsigned)__shfl_xor((int)(unsigned)rb, 1, 64);
            if (tid < 32) {
                traj[(size_t)cb * (T_ * HID_) + (t << 8) + ci] = xn;
                if ((own & 1) == 0) {
                    cstore_u32((unsigned*)(ring + (size_t)(t + 1) * 16384)
                                   + ((pair0 + own) >> 1),
                               ((unsigned)rb) | (nb << 16));
                }
                if (t == T_ - 1) xf[pair0 + own] = xn;
            }
        }

        if (grid_bar(bar, gid, (unsigned)(2 * t + 2), &abort_s)) break;
    }
}

// ======================= fallback path (known-good) =======================
__global__ __launch_bounds__(256) void gemm_step(const unsigned short* __restrict__ Wb,
                                                 const unsigned short* __restrict__ rB,
                                                 float* __restrict__ P)
{
    __shared__ unsigned short A_lds[32768];

    const int tid = threadIdx.x;
    const int l   = tid & 63;
    const int w   = tid >> 6;
    const int m   = l & 15;
    const int q   = l >> 4;
    const int ig  = blockIdx.x >> 7;
    const int c   = blockIdx.x & 127;
    const int i0  = ig << 6;

    {
        const unsigned short* src = Wb + (size_t)(i0 + (w << 4) + m) * KTOT
                                       + (c << 9) + (q << 3);
        unsigned short* dst = &A_lds[(w << 13) + (l << 3)];
        #pragma unroll
        for (int kc = 0; kc < 16; ++kc) {
            uint4 v = *(const uint4*)(src + (kc << 5));
            *(uint4*)(dst + (kc << 9)) = v;
        }
    }

    const int b = (w << 4) + m;
    const float rj0 = bf2f(rB[b * HID_ + 2 * c]);
    const float rj1 = bf2f(rB[b * HID_ + 2 * c + 1]);
    const unsigned short* rrow = rB + b * HID_ + (q << 3);

    floatx4 acc0 = {0.f, 0.f, 0.f, 0.f};
    floatx4 acc1 = {0.f, 0.f, 0.f, 0.f};
    floatx4 acc2 = {0.f, 0.f, 0.f, 0.f};
    floatx4 acc3 = {0.f, 0.f, 0.f, 0.f};

    __syncthreads();

    #pragma unroll
    for (int kc = 0; kc < 16; ++kc) {
        const float rj = (kc < 8) ? rj0 : rj1;
        const uint4 rv = *(const uint4*)(rrow + ((kc & 7) << 5));
        short8 gfrag;
        {
            unsigned int* gp = (unsigned int*)&gfrag;
            const unsigned short* rs = (const unsigned short*)&rv;
            #pragma unroll
            for (int p = 0; p < 4; ++p) {
                const float lo = bf2f(rs[2 * p])     * rj;
                const float hi = bf2f(rs[2 * p + 1]) * rj;
                gp[p] = (unsigned int)f2bf(lo) | ((unsigned int)f2bf(hi) << 16);
            }
        }
        const unsigned short* ab = &A_lds[(kc << 9) + (l << 3)];
        const short8 w0 = *(const short8*)(ab);
        const short8 w1 = *(const short8*)(ab + 8192);
        const short8 w2 = *(const short8*)(ab + 16384);
        const short8 w3 = *(const short8*)(ab + 24576);
        acc0 = __builtin_amdgcn_mfma_f32_16x16x32_bf16(gfrag, w0, acc0, 0, 0, 0);
        acc1 = __builtin_amdgcn_mfma_f32_16x16x32_bf16(gfrag, w1, acc1, 0, 0, 0);
        acc2 = __builtin_amdgcn_mfma_f32_16x16x32_bf16(gfrag, w2, acc2, 0, 0, 0);
        acc3 = __builtin_amdgcn_mfma_f32_16x16x32_bf16(gfrag, w3, acc3, 0, 0, 0);
    }

    #pragma unroll
    for (int reg = 0; reg < 4; ++reg) {
        float* dst = P + (c << 14) + ((w << 4) + (q << 2) + reg) * HID_ + i0 + m;
        dst[0]  = acc0[reg];
        dst[16] = acc1[reg];
        dst[32] = acc2[reg];
        dst[48] = acc3[reg];
    }
}

__global__ __launch_bounds__(64) void combine_step(const float* __restrict__ P,
                                                   const float* __restrict__ noise,
                                                   const float* __restrict__ u,
                                                   const float* __restrict__ W_inT,
                                                   const float* __restrict__ b_in,
                                                   float* __restrict__ x,
                                                   unsigned short* __restrict__ rB,
                                                   float* __restrict__ traj,
                                                   int t)
{
    const int b = blockIdx.x >> 2;
    const int i = ((blockIdx.x & 3) << 6) + threadIdx.x;

    __shared__ float u_s[64];
    u_s[threadIdx.x] = u[b * (T_ * IN_) + t * IN_ + threadIdx.x];
    __syncthreads();

    const float* Pp = P + b * HID_ + i;
    float s0 = 0.f, s1 = 0.f, s2 = 0.f, s3 = 0.f;
    #pragma unroll 4
    for (int cc = 0; cc < 128; cc += 4) {
        s0 += Pp[(cc + 0) * 16384];
        s1 += Pp[(cc + 1) * 16384];
        s2 += Pp[(cc + 2) * 16384];
        s3 += Pp[(cc + 3) * 16384];
    }
    const float hidden = (s0 + s1) + (s2 + s3);

    float inp = b_in[i];
    #pragma unroll
    for (int k = 0; k < 64; ++k) inp += u_s[k] * W_inT[k * HID_ + i];

    const float xo = x[b * HID_ + i];
    const float n  = noise[t * (B_ * HID_) + b * HID_ + i];
    const float xn = 0.8f * xo + 0.05f * n + 0.2f * (hidden + inp);

    x[b * HID_ + i] = xn;
    traj[(size_t)b * (T_ * HID_) + t * HID_ + i] = xn;
    rB[b * HID_ + i] = f2bf(tanhf(xn));
}

__global__ __launch_bounds__(256) void copy_xfinal(const float* __restrict__ x,
                                                   float* __restrict__ xf)
{
    const int idx = blockIdx.x * 256 + threadIdx.x;
    xf[idx] = x[idx];
}

// ---- output projection (fp32) --------------------------------------------
__global__ __launch_bounds__(256) void output_kernel(const float* __restrict__ traj,
                                                     const float* __restrict__ W_out,
                                                     const float* __restrict__ b_out,
                                                     float* __restrict__ out)
{
    __shared__ float r_s[16 * 256];
    __shared__ float Wt[64 * 65];

    const int tid = threadIdx.x;
    const int b   = blockIdx.x >> 5;
    const int t0  = (blockIdx.x & 31) << 4;

    #pragma unroll
    for (int r = 0; r < 16; ++r) {
        r_s[r * 256 + tid] = tanhf(traj[(size_t)b * (T_ * HID_) + (t0 + r) * HID_ + tid]);
    }

    const int o  = tid & 63;
    const int rg = tid >> 6;
    float acc0 = b_out[o];
    float acc1 = acc0, acc2 = acc0, acc3 = acc0;

    for (int ib = 0; ib < 4; ++ib) {
        __syncthreads();
        #pragma unroll
        for (int r = 0; r < 16; ++r) {
            const int f  = (r << 8) + tid;
            const int oo = f >> 6;
            const int il = f & 63;
            Wt[il * 65 + oo] = W_out[oo * 256 + (ib << 6) + il];
        }
        __syncthreads();
        #pragma unroll 16
        for (int il = 0; il < 64; ++il) {
            const float ww = Wt[il * 65 + o];
            const int i = (ib << 6) + il;
            acc0 += r_s[(rg * 4 + 0) * 256 + i] * ww;
            acc1 += r_s[(rg * 4 + 1) * 256 + i] * ww;
            acc2 += r_s[(rg * 4 + 2) * 256 + i] * ww;
            acc3 += r_s[(rg * 4 + 3) * 256 + i] * ww;
        }
    }
    float* ob = out + b * (T_ * IN_) + (t0 + (rg << 2)) * IN_ + o;
    ob[0 * IN_] = acc0;
    ob[1 * IN_] = acc1;
    ob[2 * IN_] = acc2;
    ob[3 * IN_] = acc3;
}

extern "C" void kernel_launch(void* const* d_in, const int* in_sizes, int n_in,
                              void* d_out, int out_size, void* d_ws, size_t ws_size,
                              hipStream_t stream)
{
    const float* u     = (const float*)d_in[0];
    const float* x0    = (const float*)d_in[1];
    const float* noise = (const float*)d_in[2];
    const float* W_hh  = (const float*)d_in[3];
    const float* W_in  = (const float*)d_in[4];
    const float* b_in  = (const float*)d_in[5];
    const float* W_out = (const float*)d_in[6];
    const float* b_out = (const float*)d_in[7];

    float* out  = (float*)d_out;
    float* xf   = out + 2097152;            // [B][HID]
    float* traj = out + 2097152 + 16384;    // [B][T][HID]

    // ws byte layout:
    //   P     : 0           (8 MB region; coop uses first 2 MB)
    //   ring  : 8,388,608   (513 x 32768 = 16,809,984)   [coop]
    //   Wb    : 8,388,608   (33,554,432)                 [fallback, overlaps ring]
    //   W_inT : 41,943,040  (65,536)
    //   bar   : 42,008,576  (4,096)
    //   rB_fb : 42,012,672  (32,768)                     [fallback]
    //   x_fb  : 42,045,440  (65,536)                     [fallback]
    //   pre   : 42,110,976  (33,554,432)                 [optional]
    char* wsb = (char*)d_ws;
    float*          P     = (float*)(wsb);
    unsigned short* ring  = (unsigned short*)(wsb + 8388608ull);
    unsigned short* Wb    = (unsigned short*)(wsb + 8388608ull);
    float*          W_inT = (float*)(wsb + 41943040ull);
    unsigned*       bar   = (unsigned*)(wsb + 42008576ull);
    unsigned short* rB_fb = (unsigned short*)(wsb + 42012672ull);
    float*          x     = (float*)(wsb + 42045440ull);
    float*          pre   = (float*)(wsb + 42110976ull);
    const int use_pre = (ws_size >= 42110976ull + 33554432ull) ? 1 : 0;

    init_kernel<<<64, 256, 0, stream>>>(x0, W_in, ring, W_inT, bar);
    if (use_pre) pre_kernel<<<256, 256, 0, stream>>>(u, W_inT, b_in, noise, pre);

    // ---- persistent cooperative path ----
    {
        const float*          a_W    = W_hh;
        unsigned short*       a_ring = ring;
        float*                a_P    = P;
        const float*          a_pre  = pre;
        const float*          a_u    = u;
        const float*          a_WinT = W_inT;
        const float*          a_bin  = b_in;
        const float*          a_nz   = noise;
        const float*          a_x0   = x0;
        float*                a_traj = traj;
        float*                a_xf   = xf;
        unsigned*             a_bar  = bar;
        int                   a_up   = use_pre;
        void* args[] = { &a_W, &a_ring, &a_P, &a_pre, &a_u, &a_WinT, &a_bin,
                         &a_nz, &a_x0, &a_traj, &a_xf, &a_bar, &a_up };
        hipError_t e = hipLaunchCooperativeKernel(persist_kernel, dim3(512), dim3(256),
                                                  args, 0, stream);
        if (e == hipSuccess) {
            output_kernel<<<2048, 256, 0, stream>>>(traj, W_out, b_out, out);
            return;
        }
    }

    // ---- fallback: per-step launches (known-good path) ----
    conv_w<<<16384, 256, 0, stream>>>(W_hh, Wb);   // clobbers ring (unused here)
    init_kernel<<<64, 256, 0, stream>>>(x0, W_in, rB_fb, W_inT, bar);
    init_x<<<64, 256, 0, stream>>>(x0, x);
    for (int t = 0; t < T_; ++t) {
        gemm_step<<<512, 256, 0, stream>>>(Wb, rB_fb, P);
        combine_step<<<256, 64, 0, stream>>>(P, noise, u, W_inT, b_in, x, rB_fb, traj, t);
    }
    copy_xfinal<<<64, 256, 0, stream>>>(x, xf);
    output_kernel<<<2048, 256, 0, stream>>>(traj, W_out, b_out, out);
}